// Round 1
// baseline (2775.969 us; speedup 1.0000x reference)
//
#include <hip/hip_runtime.h>

typedef _Float16 half8 __attribute__((ext_vector_type(8)));
typedef float floatx4 __attribute__((ext_vector_type(4)));

#define DEV_INLINE __device__ __forceinline__

constexpr int D0 = 512, D1 = 256, D2 = 256, D3 = 128;
constexpr int NROWS = 16384;
constexpr int MBLK = 64;            // batch rows per block
constexpr int NBLK = NROWS / MBLK;  // 256 blocks == #CUs
constexpr int KITERS = 16;
constexpr float ETA = 0.1f;

// packed-weight element offsets (fp16 elements) inside d_ws
constexpr int OFF_WF0 = 0;                  // fwd W0: K=256, N=512
constexpr int OFF_WF1 = OFF_WF0 + D1 * D0;  // fwd W1: K=256, N=256
constexpr int OFF_WF2 = OFF_WF1 + D2 * D1;  // fwd W2: K=128, N=256
constexpr int OFF_WB0 = OFF_WF2 + D3 * D2;  // bwd W0^T: K=512, N=256
constexpr int OFF_WB1 = OFF_WB0 + D0 * D1;  // bwd W1^T: K=256, N=256
constexpr int OFF_WB2 = OFF_WB1 + D1 * D2;  // bwd W2^T: K=256, N=128
constexpr int PACK_ELEMS = OFF_WB2 + D2 * D3;  // 458752 elems = 896 KB fp16

// ---------------------------------------------------------------------------
// Repack weights into MFMA B-fragment order + cast x0 to fp16.
// B-frag layout (16x16x32): lane l supplies B[kt*32 + (l>>4)*8 + j][nt*16 + (l&15)],
// j=0..7 contiguous -> pack index ((kt*NT + nt)*64 + l)*8 + j.
// ---------------------------------------------------------------------------
__global__ void repack_kernel(const float* __restrict__ W0, const float* __restrict__ W1,
                              const float* __restrict__ W2, const float* __restrict__ x0,
                              _Float16* __restrict__ pack, _Float16* __restrict__ x0h,
                              int do_x0) {
  int p = blockIdx.x * 256 + threadIdx.x;
  if (p < PACK_ELEMS) {
    const float* W; int Csrc, Nd, off; bool tr;
    if (p < OFF_WF1)      { W = W0; Csrc = D0; Nd = D0; off = OFF_WF0; tr = false; }
    else if (p < OFF_WF2) { W = W1; Csrc = D1; Nd = D1; off = OFF_WF1; tr = false; }
    else if (p < OFF_WB0) { W = W2; Csrc = D2; Nd = D2; off = OFF_WF2; tr = false; }
    else if (p < OFF_WB1) { W = W0; Csrc = D0; Nd = D1; off = OFF_WB0; tr = true;  }
    else if (p < OFF_WB2) { W = W1; Csrc = D1; Nd = D1; off = OFF_WB1; tr = true;  }
    else                  { W = W2; Csrc = D2; Nd = D3; off = OFF_WB2; tr = true;  }
    int local = p - off;
    int j  = local & 7;
    int l  = (local >> 3) & 63;
    int fr = local >> 9;
    int NT = Nd >> 4;
    int nt = fr % NT, kt = fr / NT;
    int k = kt * 32 + ((l >> 4) << 3) + j;
    int n = nt * 16 + (l & 15);
    float v = tr ? W[n * Csrc + k] : W[k * Csrc + n];
    pack[p] = (_Float16)v;
  } else if (do_x0) {
    int q = p - PACK_ELEMS;
    if (q < NROWS * D0) x0h[q] = (_Float16)x0[q];
  }
}

DEV_INLINE float fast_tanh(float x) {
  float e = __expf(2.f * x);                       // v_exp_f32
  return 1.f - 2.f * __builtin_amdgcn_rcpf(e + 1.f);
}

// ---------------------------------------------------------------------------
// Generic tiled matmul: OUT(64 x NTT*16) += A(64 x KSTEPS*32) @ Bpacked.
// 8 waves; each wave owns all 4 row-tiles x CT col-tiles (no redundant B fetch).
// A in LDS, fp16, row stride STRB bytes, XOR-swizzled by ((row&7)<<4).
// ---------------------------------------------------------------------------
template <int KSTEPS, int NTT, int CT, int STRB>
DEV_INLINE void mm_tiles(const char* __restrict__ A, const _Float16* __restrict__ Bp,
                         int lane, int wave, floatx4* acc) {
  const int arow = lane & 15;
  const int aoff = (lane >> 4) << 4;  // byte offset of this lane's 16B k-chunk
#pragma unroll
  for (int kt = 0; kt < KSTEPS; ++kt) {
    half8 a[4];
#pragma unroll
    for (int rt = 0; rt < 4; ++rt) {
      int row = rt * 16 + arow;
      int byte = (row * STRB + kt * 64 + aoff) ^ ((row & 7) << 4);
      a[rt] = *(const half8*)(A + byte);
    }
#pragma unroll
    for (int ct = 0; ct < CT; ++ct) {
      const half8 b = *(const half8*)(Bp + (((kt * NTT) + (wave * CT + ct)) * 64 + lane) * 8);
#pragma unroll
      for (int rt = 0; rt < 4; ++rt)
        acc[rt * CT + ct] =
            __builtin_amdgcn_mfma_f32_16x16x32_f16(a[rt], b, acc[rt * CT + ct], 0, 0, 0);
    }
  }
}

// ---------------------------------------------------------------------------
// Persistent settling kernel. LDS arenas (128 KB dynamic):
//   P [64KB]: x1 [64][256] (stride 512B)  <-> g0 [64][512] (stride 1024B)
//   Q [32KB]: x2 [64][256]                <-> g1 [64][256]
//   R [32KB]: x3 [64][128] (stride 256B)  <-> g2 [64][256] (stride 512B)
// Phase order per iter: ph3(preact0->g0), ph1(preact1->e1,g1), ph4(dx1->x1),
//                       ph2(preact2->e2,g2), ph5(dx2->x2), ph6(dx3->x3).
// ---------------------------------------------------------------------------
__global__ __launch_bounds__(512, 2) void settle_kernel(const float* __restrict__ x0,
                                                        const _Float16* __restrict__ x0h,
                                                        const _Float16* __restrict__ pack,
                                                        float* __restrict__ out) {
  extern __shared__ char lds[];
  char* P = lds;
  char* Q = lds + 65536;
  char* R = lds + 98304;

  const int tid  = threadIdx.x;
  const int lane = tid & 63;
  const int wave = tid >> 6;
  const int row0 = blockIdx.x * MBLK;
  const int rsub = (lane >> 4) << 2;  // C/D layout: row = (lane>>4)*4 + i
  const int csub = lane & 15;         //             col = lane & 15

  // zero-init x1, x2, x3 LDS images
  {
    floatx4 z = {0.f, 0.f, 0.f, 0.f};
    for (int i = tid; i < 2048; i += 512) ((floatx4*)P)[i] = z;
    for (int i = tid; i < 2048; i += 512) ((floatx4*)Q)[i] = z;
    for (int i = tid; i < 1024; i += 512) ((floatx4*)R)[i] = z;
  }
  __syncthreads();

  const floatx4 zf = {0.f, 0.f, 0.f, 0.f};
  floatx4 x1m[8], x2m[8], x3m[4];  // fp32 master states at C-layout
  floatx4 dx1a[8], dx2a[8];        // carry preact -> (-e) -> dx accumulators
#pragma unroll
  for (int i = 0; i < 8; ++i) { x1m[i] = zf; x2m[i] = zf; }
#pragma unroll
  for (int i = 0; i < 4; ++i) x3m[i] = zf;

  const _Float16* Wf0 = pack + OFF_WF0;
  const _Float16* Wf1 = pack + OFF_WF1;
  const _Float16* Wf2 = pack + OFF_WF2;
  const _Float16* Wb0 = pack + OFF_WB0;
  const _Float16* Wb1 = pack + OFF_WB1;
  const _Float16* Wb2 = pack + OFF_WB2;

  for (int it = 0; it < KITERS; ++it) {
    // ---- ph3: preact0 = x1 @ W0 (N=512); g0 = (x0 - tanh)*(1-t^2) -> P
    {
      floatx4 acc[16];
#pragma unroll
      for (int i = 0; i < 16; ++i) acc[i] = zf;
      mm_tiles<8, 32, 4, 512>(P, Wf0, lane, wave, acc);
      __syncthreads();  // all x1 reads done before g0 overwrites P
#pragma unroll
      for (int rt = 0; rt < 4; ++rt)
#pragma unroll
        for (int ct = 0; ct < 4; ++ct) {
          int col = (wave * 4 + ct) * 16 + csub;
#pragma unroll
          for (int i = 0; i < 4; ++i) {
            int row = rt * 16 + rsub + i;
            float t = fast_tanh(acc[rt * 4 + ct][i]);
            size_t gi = (size_t)(row0 + row) * D0 + col;
            float xv = x0h ? (float)x0h[gi] : x0[gi];
            float g = (xv - t) * (1.f - t * t);
            int byte = (row * 1024 + col * 2) ^ ((row & 7) << 4);
            *(_Float16*)(P + byte) = (_Float16)g;
          }
        }
      __syncthreads();
    }
    // ---- ph1: preact1 = x2 @ W1; e1 = x1 - tanh; g1 -> Q; dx1a = -e1
    {
#pragma unroll
      for (int i = 0; i < 8; ++i) dx1a[i] = zf;
      mm_tiles<8, 16, 2, 512>(Q, Wf1, lane, wave, dx1a);
      __syncthreads();
#pragma unroll
      for (int rt = 0; rt < 4; ++rt)
#pragma unroll
        for (int ct = 0; ct < 2; ++ct) {
          int col = (wave * 2 + ct) * 16 + csub;
#pragma unroll
          for (int i = 0; i < 4; ++i) {
            int row = rt * 16 + rsub + i;
            float t = fast_tanh(dx1a[rt * 2 + ct][i]);
            float e = x1m[rt * 2 + ct][i] - t;
            float g = e * (1.f - t * t);
            int byte = (row * 512 + col * 2) ^ ((row & 7) << 4);
            *(_Float16*)(Q + byte) = (_Float16)g;
            dx1a[rt * 2 + ct][i] = -e;
          }
        }
      __syncthreads();
    }
    // ---- ph4: dx1a += g0 @ W0^T (K=512); x1 += eta*clip; x1 -> P
    {
      mm_tiles<16, 16, 2, 1024>(P, Wb0, lane, wave, dx1a);
      __syncthreads();
#pragma unroll
      for (int rt = 0; rt < 4; ++rt)
#pragma unroll
        for (int ct = 0; ct < 2; ++ct) {
          int col = (wave * 2 + ct) * 16 + csub;
#pragma unroll
          for (int i = 0; i < 4; ++i) {
            int row = rt * 16 + rsub + i;
            float dx = fminf(1.f, fmaxf(-1.f, dx1a[rt * 2 + ct][i]));
            float nv = x1m[rt * 2 + ct][i] + ETA * dx;
            x1m[rt * 2 + ct][i] = nv;
            int byte = (row * 512 + col * 2) ^ ((row & 7) << 4);
            *(_Float16*)(P + byte) = (_Float16)nv;
          }
        }
      __syncthreads();
    }
    // ---- ph2: preact2 = x3 @ W2 (K=128); e2 = x2 - tanh; g2 -> R; dx2a = -e2
    {
#pragma unroll
      for (int i = 0; i < 8; ++i) dx2a[i] = zf;
      mm_tiles<4, 16, 2, 256>(R, Wf2, lane, wave, dx2a);
      __syncthreads();
#pragma unroll
      for (int rt = 0; rt < 4; ++rt)
#pragma unroll
        for (int ct = 0; ct < 2; ++ct) {
          int col = (wave * 2 + ct) * 16 + csub;
#pragma unroll
          for (int i = 0; i < 4; ++i) {
            int row = rt * 16 + rsub + i;
            float t = fast_tanh(dx2a[rt * 2 + ct][i]);
            float e = x2m[rt * 2 + ct][i] - t;
            float g = e * (1.f - t * t);
            int byte = (row * 512 + col * 2) ^ ((row & 7) << 4);
            *(_Float16*)(R + byte) = (_Float16)g;
            dx2a[rt * 2 + ct][i] = -e;
          }
        }
      __syncthreads();
    }
    // ---- ph5: dx2a += g1 @ W1^T; x2 += eta*clip; x2 -> Q
    {
      mm_tiles<8, 16, 2, 512>(Q, Wb1, lane, wave, dx2a);
      __syncthreads();
#pragma unroll
      for (int rt = 0; rt < 4; ++rt)
#pragma unroll
        for (int ct = 0; ct < 2; ++ct) {
          int col = (wave * 2 + ct) * 16 + csub;
#pragma unroll
          for (int i = 0; i < 4; ++i) {
            int row = rt * 16 + rsub + i;
            float dx = fminf(1.f, fmaxf(-1.f, dx2a[rt * 2 + ct][i]));
            float nv = x2m[rt * 2 + ct][i] + ETA * dx;
            x2m[rt * 2 + ct][i] = nv;
            int byte = (row * 512 + col * 2) ^ ((row & 7) << 4);
            *(_Float16*)(Q + byte) = (_Float16)nv;
          }
        }
      __syncthreads();
    }
    // ---- ph6: dx3 = g2 @ W2^T (N=128); x3 += eta*clip; x3 -> R
    {
      floatx4 acc[4];
#pragma unroll
      for (int i = 0; i < 4; ++i) acc[i] = zf;
      mm_tiles<8, 8, 1, 512>(R, Wb2, lane, wave, acc);
      __syncthreads();
#pragma unroll
      for (int rt = 0; rt < 4; ++rt) {
        int col = wave * 16 + csub;
#pragma unroll
        for (int i = 0; i < 4; ++i) {
          int row = rt * 16 + rsub + i;
          float dx = fminf(1.f, fmaxf(-1.f, acc[rt][i]));
          float nv = x3m[rt][i] + ETA * dx;
          x3m[rt][i] = nv;
          int byte = (row * 256 + col * 2) ^ ((row & 7) << 4);
          *(_Float16*)(R + byte) = (_Float16)nv;
        }
      }
      __syncthreads();
    }
  }

  // write settled x3 (fp32)
#pragma unroll
  for (int rt = 0; rt < 4; ++rt) {
    int col = wave * 16 + csub;
#pragma unroll
    for (int i = 0; i < 4; ++i) {
      int row = rt * 16 + rsub + i;
      out[(size_t)(row0 + row) * D3 + col] = x3m[rt][i];
    }
  }
}

extern "C" void kernel_launch(void* const* d_in, const int* in_sizes, int n_in,
                              void* d_out, int out_size, void* d_ws, size_t ws_size,
                              hipStream_t stream) {
  const float* x0 = (const float*)d_in[0];
  const float* W0 = (const float*)d_in[1];
  const float* W1 = (const float*)d_in[2];
  const float* W2 = (const float*)d_in[3];
  float* out = (float*)d_out;

  _Float16* pack = (_Float16*)d_ws;
  const size_t pack_bytes = (size_t)PACK_ELEMS * 2;
  const size_t x0h_bytes = (size_t)NROWS * D0 * 2;
  int do_x0 = (ws_size >= pack_bytes + x0h_bytes) ? 1 : 0;
  _Float16* x0h = do_x0 ? (_Float16*)((char*)d_ws + pack_bytes) : nullptr;

  int total = PACK_ELEMS + (do_x0 ? NROWS * D0 : 0);
  repack_kernel<<<(total + 255) / 256, 256, 0, stream>>>(W0, W1, W2, x0, pack, x0h, do_x0);

  (void)hipFuncSetAttribute(reinterpret_cast<const void*>(settle_kernel),
                            hipFuncAttributeMaxDynamicSharedMemorySize, 131072);
  settle_kernel<<<NBLK, 512, 131072, stream>>>(x0, x0h, pack, out);
}

// Round 2
// 2769.644 us; speedup vs baseline: 1.0023x; 1.0023x over previous
//
#include <hip/hip_runtime.h>

typedef _Float16 half8 __attribute__((ext_vector_type(8)));
typedef float floatx4 __attribute__((ext_vector_type(4)));

#define DEV_INLINE __device__ __forceinline__

constexpr int D0 = 512, D1 = 256, D2 = 256, D3 = 128;
constexpr int NROWS = 16384;
constexpr int MBLK = 64;            // batch rows per block
constexpr int NBLK = NROWS / MBLK;  // 256 blocks == #CUs
constexpr int KITERS = 16;
constexpr float ETA = 0.1f;

// packed-weight element offsets (fp16 elements) inside d_ws
constexpr int OFF_WF0 = 0;                  // fwd W0: K=256, N=512
constexpr int OFF_WF1 = OFF_WF0 + D1 * D0;  // fwd W1: K=256, N=256
constexpr int OFF_WF2 = OFF_WF1 + D2 * D1;  // fwd W2: K=128, N=256
constexpr int OFF_WB0 = OFF_WF2 + D3 * D2;  // bwd W0^T: K=512, N=256
constexpr int OFF_WB1 = OFF_WB0 + D0 * D1;  // bwd W1^T: K=256, N=256
constexpr int OFF_WB2 = OFF_WB1 + D1 * D2;  // bwd W2^T: K=256, N=128
constexpr int PACK_ELEMS = OFF_WB2 + D2 * D3;  // 458752 elems = 896 KB fp16

// ---------------------------------------------------------------------------
// Repack weights into MFMA B-fragment order.
// B-frag layout (16x16x32): lane l supplies B[kt*32 + (l>>4)*8 + j][nt*16 + (l&15)],
// j=0..7 contiguous -> pack index ((kt*NT + nt)*64 + l)*8 + j.
// ---------------------------------------------------------------------------
__global__ void repack_kernel(const float* __restrict__ W0, const float* __restrict__ W1,
                              const float* __restrict__ W2, _Float16* __restrict__ pack) {
  int p = blockIdx.x * 256 + threadIdx.x;
  if (p >= PACK_ELEMS) return;
  const float* W; int Csrc, Nd, off; bool tr;
  if (p < OFF_WF1)      { W = W0; Csrc = D0; Nd = D0; off = OFF_WF0; tr = false; }
  else if (p < OFF_WF2) { W = W1; Csrc = D1; Nd = D1; off = OFF_WF1; tr = false; }
  else if (p < OFF_WB0) { W = W2; Csrc = D2; Nd = D2; off = OFF_WF2; tr = false; }
  else if (p < OFF_WB1) { W = W0; Csrc = D0; Nd = D1; off = OFF_WB0; tr = true;  }
  else if (p < OFF_WB2) { W = W1; Csrc = D1; Nd = D1; off = OFF_WB1; tr = true;  }
  else                  { W = W2; Csrc = D2; Nd = D3; off = OFF_WB2; tr = true;  }
  int local = p - off;
  int j  = local & 7;
  int l  = (local >> 3) & 63;
  int fr = local >> 9;
  int NT = Nd >> 4;
  int nt = fr % NT, kt = fr / NT;
  int k = kt * 32 + ((l >> 4) << 3) + j;
  int n = nt * 16 + (l & 15);
  float v = tr ? W[n * Csrc + k] : W[k * Csrc + n];
  pack[p] = (_Float16)v;
}

DEV_INLINE float fast_tanh(float x) {
  float e = __expf(2.f * x);                       // v_exp_f32
  return 1.f - 2.f * __builtin_amdgcn_rcpf(e + 1.f);
}

// ---------------------------------------------------------------------------
// Tiled matmul: OUT(64 x NTT*16) += A(64 x KSTEPS*32) @ Bpacked.
// B-fragments are batch-prefetched into registers (GK*CT frags = up to 32 VGPR)
// so the global loads pipeline instead of serializing against MFMA.
// A in LDS, fp16, row stride STRB bytes, XOR-swizzled by ((row&7)<<4).
// ---------------------------------------------------------------------------
template <int KSTEPS, int NTT, int CT, int STRB, int GK>
DEV_INLINE void mm_tiles(const char* __restrict__ A, const _Float16* __restrict__ Bp,
                         int lane, int wave, floatx4* acc) {
  const int arow = lane & 15;
  const int aoff = (lane >> 4) << 4;  // byte offset of this lane's 16B k-chunk
#pragma unroll
  for (int k0 = 0; k0 < KSTEPS; k0 += GK) {
    half8 bq[GK * CT];
#pragma unroll
    for (int g = 0; g < GK; ++g)
#pragma unroll
      for (int ct = 0; ct < CT; ++ct)
        bq[g * CT + ct] =
            *(const half8*)(Bp + ((((k0 + g) * NTT) + (wave * CT + ct)) * 64 + lane) * 8);
#pragma unroll
    for (int g = 0; g < GK; ++g) {
      half8 a[4];
#pragma unroll
      for (int rt = 0; rt < 4; ++rt) {
        int row = rt * 16 + arow;
        int byte = (row * STRB + (k0 + g) * 64 + aoff) ^ ((row & 7) << 4);
        a[rt] = *(const half8*)(A + byte);
      }
#pragma unroll
      for (int ct = 0; ct < CT; ++ct)
#pragma unroll
        for (int rt = 0; rt < 4; ++rt)
          acc[rt * CT + ct] =
              __builtin_amdgcn_mfma_f32_16x16x32_f16(a[rt], bq[g * CT + ct], acc[rt * CT + ct], 0, 0, 0);
    }
  }
}

// ---------------------------------------------------------------------------
// Persistent settling kernel. LDS arenas (128 KB dynamic):
//   P [64KB]: x1 [64][256] (stride 512B)  <-> g0 [64][512] (stride 1024B)
//   Q [32KB]: x2 [64][256]                <-> g1 [64][256]
//   R [32KB]: x3 [64][128] (stride 256B)  <-> g2 [64][256] (stride 512B)
// Phase order per iter: ph3(preact0->g0), ph1(preact1->e1,g1), ph4(dx1->x1),
//                       ph2(preact2->e2,g2), ph5(dx2->x2), ph6(dx3->x3).
// Single barrier per phase (mid-phase WAR); all cross-phase RAW/WAR verified
// disjoint within each barrier interval.
// ---------------------------------------------------------------------------
__global__ __launch_bounds__(512, 2) void settle_kernel(const float* __restrict__ x0,
                                                        const _Float16* __restrict__ pack,
                                                        float* __restrict__ out) {
  extern __shared__ char lds[];
  char* P = lds;
  char* Q = lds + 65536;
  char* R = lds + 98304;

  const int tid  = threadIdx.x;
  const int lane = tid & 63;
  const int wave = tid >> 6;
  const int row0 = blockIdx.x * MBLK;
  const int rsub = (lane >> 4) << 2;  // C/D layout: row = (lane>>4)*4 + i
  const int csub = lane & 15;         //             col = lane & 15

  // ---- preload this block's x0 tile into registers at the ph3-epilogue
  // C-layout: x0r[(rt*4+ct)*4+i] = x0[row0 + rt*16 + rsub + i][(wave*4+ct)*16 + csub]
  half8 x0r[8];
#pragma unroll
  for (int rt = 0; rt < 4; ++rt)
#pragma unroll
    for (int ct = 0; ct < 4; ++ct)
#pragma unroll
      for (int i = 0; i < 4; ++i) {
        float v = x0[(size_t)(row0 + rt * 16 + rsub + i) * D0 + (wave * 4 + ct) * 16 + csub];
        int li = (rt * 4 + ct) * 4 + i;
        x0r[li >> 3][li & 7] = (_Float16)v;
      }

  // zero-init x2 (Q) and x3 (R) LDS images; P gets g0 = x0 below
  {
    floatx4 z = {0.f, 0.f, 0.f, 0.f};
    for (int i = tid; i < 2048; i += 512) ((floatx4*)Q)[i] = z;
    for (int i = tid; i < 2048; i += 512) ((floatx4*)R)[i] = z;
  }

  const floatx4 zf = {0.f, 0.f, 0.f, 0.f};
  floatx4 x1m[8], x2m[8], x3m[4];  // fp32 master states at C-layout
  floatx4 dx1a[8], dx2a[8];        // carry preact -> (-e) -> dx accumulators
#pragma unroll
  for (int i = 0; i < 8; ++i) { x1m[i] = zf; x2m[i] = zf; }
#pragma unroll
  for (int i = 0; i < 4; ++i) x3m[i] = zf;

  const _Float16* Wf0 = pack + OFF_WF0;
  const _Float16* Wf1 = pack + OFF_WF1;
  const _Float16* Wf2 = pack + OFF_WF2;
  const _Float16* Wb0 = pack + OFF_WB0;
  const _Float16* Wb1 = pack + OFF_WB1;
  const _Float16* Wb2 = pack + OFF_WB2;

  // =================== iteration 0 shortcut ===================
  // states are zero: g0 = x0 (f'(0)=1), e1=e2=0, dx2=dx3=0.
  // Only dx1 = x0 @ W0^T is nonzero.
#pragma unroll
  for (int rt = 0; rt < 4; ++rt)
#pragma unroll
    for (int ct = 0; ct < 4; ++ct) {
      int col = (wave * 4 + ct) * 16 + csub;
#pragma unroll
      for (int i = 0; i < 4; ++i) {
        int row = rt * 16 + rsub + i;
        int li = (rt * 4 + ct) * 4 + i;
        int byte = (row * 1024 + col * 2) ^ ((row & 7) << 4);
        *(_Float16*)(P + byte) = x0r[li >> 3][li & 7];
      }
    }
  __syncthreads();
  {
#pragma unroll
    for (int i = 0; i < 8; ++i) dx1a[i] = zf;
    mm_tiles<16, 16, 2, 1024, 4>(P, Wb0, lane, wave, dx1a);
    __syncthreads();
#pragma unroll
    for (int rt = 0; rt < 4; ++rt)
#pragma unroll
      for (int ct = 0; ct < 2; ++ct) {
        int col = (wave * 2 + ct) * 16 + csub;
#pragma unroll
        for (int i = 0; i < 4; ++i) {
          int row = rt * 16 + rsub + i;
          float dx = fminf(1.f, fmaxf(-1.f, dx1a[rt * 2 + ct][i]));
          float nv = ETA * dx;
          x1m[rt * 2 + ct][i] = nv;
          int byte = (row * 512 + col * 2) ^ ((row & 7) << 4);
          *(_Float16*)(P + byte) = (_Float16)nv;
        }
      }
    __syncthreads();
  }

  // =================== iterations 1..15 ===================
  for (int it = 1; it < KITERS; ++it) {
    // ---- ph3: preact0 = x1 @ W0 (N=512); g0 = (x0 - tanh)*(1-t^2) -> P
    {
      floatx4 acc[16];
#pragma unroll
      for (int i = 0; i < 16; ++i) acc[i] = zf;
      mm_tiles<8, 32, 4, 512, 2>(P, Wf0, lane, wave, acc);
      __syncthreads();  // all x1 reads done before g0 overwrites P
#pragma unroll
      for (int rt = 0; rt < 4; ++rt)
#pragma unroll
        for (int ct = 0; ct < 4; ++ct) {
          int col = (wave * 4 + ct) * 16 + csub;
#pragma unroll
          for (int i = 0; i < 4; ++i) {
            int row = rt * 16 + rsub + i;
            int li = (rt * 4 + ct) * 4 + i;
            float t = fast_tanh(acc[rt * 4 + ct][i]);
            float xv = (float)x0r[li >> 3][li & 7];
            float g = (xv - t) * (1.f - t * t);
            int byte = (row * 1024 + col * 2) ^ ((row & 7) << 4);
            *(_Float16*)(P + byte) = (_Float16)g;
          }
        }
    }
    // ---- ph1: preact1 = x2 @ W1; e1 = x1 - tanh; g1 -> Q; dx1a = -e1
    {
#pragma unroll
      for (int i = 0; i < 8; ++i) dx1a[i] = zf;
      mm_tiles<8, 16, 2, 512, 4>(Q, Wf1, lane, wave, dx1a);
      __syncthreads();
#pragma unroll
      for (int rt = 0; rt < 4; ++rt)
#pragma unroll
        for (int ct = 0; ct < 2; ++ct) {
          int col = (wave * 2 + ct) * 16 + csub;
#pragma unroll
          for (int i = 0; i < 4; ++i) {
            int row = rt * 16 + rsub + i;
            float t = fast_tanh(dx1a[rt * 2 + ct][i]);
            float e = x1m[rt * 2 + ct][i] - t;
            float g = e * (1.f - t * t);
            int byte = (row * 512 + col * 2) ^ ((row & 7) << 4);
            *(_Float16*)(Q + byte) = (_Float16)g;
            dx1a[rt * 2 + ct][i] = -e;
          }
        }
    }
    // ---- ph4: dx1a += g0 @ W0^T (K=512); x1 += eta*clip; x1 -> P
    {
      mm_tiles<16, 16, 2, 1024, 4>(P, Wb0, lane, wave, dx1a);
      __syncthreads();
#pragma unroll
      for (int rt = 0; rt < 4; ++rt)
#pragma unroll
        for (int ct = 0; ct < 2; ++ct) {
          int col = (wave * 2 + ct) * 16 + csub;
#pragma unroll
          for (int i = 0; i < 4; ++i) {
            int row = rt * 16 + rsub + i;
            float dx = fminf(1.f, fmaxf(-1.f, dx1a[rt * 2 + ct][i]));
            float nv = x1m[rt * 2 + ct][i] + ETA * dx;
            x1m[rt * 2 + ct][i] = nv;
            int byte = (row * 512 + col * 2) ^ ((row & 7) << 4);
            *(_Float16*)(P + byte) = (_Float16)nv;
          }
        }
    }
    // ---- ph2: preact2 = x3 @ W2 (K=128); e2 = x2 - tanh; g2 -> R; dx2a = -e2
    {
#pragma unroll
      for (int i = 0; i < 8; ++i) dx2a[i] = zf;
      mm_tiles<4, 16, 2, 256, 4>(R, Wf2, lane, wave, dx2a);
      __syncthreads();
#pragma unroll
      for (int rt = 0; rt < 4; ++rt)
#pragma unroll
        for (int ct = 0; ct < 2; ++ct) {
          int col = (wave * 2 + ct) * 16 + csub;
#pragma unroll
          for (int i = 0; i < 4; ++i) {
            int row = rt * 16 + rsub + i;
            float t = fast_tanh(dx2a[rt * 2 + ct][i]);
            float e = x2m[rt * 2 + ct][i] - t;
            float g = e * (1.f - t * t);
            int byte = (row * 512 + col * 2) ^ ((row & 7) << 4);
            *(_Float16*)(R + byte) = (_Float16)g;
            dx2a[rt * 2 + ct][i] = -e;
          }
        }
    }
    // ---- ph5: dx2a += g1 @ W1^T; x2 += eta*clip; x2 -> Q
    {
      mm_tiles<8, 16, 2, 512, 4>(Q, Wb1, lane, wave, dx2a);
      __syncthreads();
#pragma unroll
      for (int rt = 0; rt < 4; ++rt)
#pragma unroll
        for (int ct = 0; ct < 2; ++ct) {
          int col = (wave * 2 + ct) * 16 + csub;
#pragma unroll
          for (int i = 0; i < 4; ++i) {
            int row = rt * 16 + rsub + i;
            float dx = fminf(1.f, fmaxf(-1.f, dx2a[rt * 2 + ct][i]));
            float nv = x2m[rt * 2 + ct][i] + ETA * dx;
            x2m[rt * 2 + ct][i] = nv;
            int byte = (row * 512 + col * 2) ^ ((row & 7) << 4);
            *(_Float16*)(Q + byte) = (_Float16)nv;
          }
        }
    }
    // ---- ph6: dx3 = g2 @ W2^T (N=128); x3 += eta*clip; x3 -> R
    {
      floatx4 acc[4];
#pragma unroll
      for (int i = 0; i < 4; ++i) acc[i] = zf;
      mm_tiles<8, 8, 1, 512, 8>(R, Wb2, lane, wave, acc);
      __syncthreads();
#pragma unroll
      for (int rt = 0; rt < 4; ++rt) {
        int col = wave * 16 + csub;
#pragma unroll
        for (int i = 0; i < 4; ++i) {
          int row = rt * 16 + rsub + i;
          float dx = fminf(1.f, fmaxf(-1.f, acc[rt][i]));
          float nv = x3m[rt][i] + ETA * dx;
          x3m[rt][i] = nv;
          int byte = (row * 256 + col * 2) ^ ((row & 7) << 4);
          *(_Float16*)(R + byte) = (_Float16)nv;
        }
      }
      __syncthreads();  // ep6 writes R(x3); next-iter ph3 reads P -- but keep
                        // one barrier so prologue of next iter can't race R zeroing
    }
  }

  // write settled x3 (fp32)
#pragma unroll
  for (int rt = 0; rt < 4; ++rt) {
    int col = wave * 16 + csub;
#pragma unroll
    for (int i = 0; i < 4; ++i) {
      int row = rt * 16 + rsub + i;
      out[(size_t)(row0 + row) * D3 + col] = x3m[rt][i];
    }
  }
}

extern "C" void kernel_launch(void* const* d_in, const int* in_sizes, int n_in,
                              void* d_out, int out_size, void* d_ws, size_t ws_size,
                              hipStream_t stream) {
  const float* x0 = (const float*)d_in[0];
  const float* W0 = (const float*)d_in[1];
  const float* W1 = (const float*)d_in[2];
  const float* W2 = (const float*)d_in[3];
  float* out = (float*)d_out;

  _Float16* pack = (_Float16*)d_ws;
  repack_kernel<<<(PACK_ELEMS + 255) / 256, 256, 0, stream>>>(W0, W1, W2, pack);

  (void)hipFuncSetAttribute(reinterpret_cast<const void*>(settle_kernel),
                            hipFuncAttributeMaxDynamicSharedMemorySize, 131072);
  settle_kernel<<<NBLK, 512, 131072, stream>>>(x0, pack, out);
}